// Round 11
// baseline (168.134 us; speedup 1.0000x reference)
//
#include <hip/hip_runtime.h>
#include <math.h>

#define NWAY 5
#define KSHOT 5
#define PRJ 14
#define DD 64
#define PP 100
#define NQ 1024
#define NS 350
#define NPAIR 70
#define LAMDA 32.0f
#define MARGIN 0.3f
#define PCHUNK 25
#define FGROUPS 80
#define KCH 80

// ---- workspace layout (floats), ~42.2 MB ----
#define VPT_OFF   0          // [70][100][64]  = 448000  ([p][d])
#define VPTS_OFF  448000     // [350][6400]    = 2240000
#define B2T_OFF   2688000    // [70][6400]     = 448000  (f = d*100+p contiguous)
#define MM_OFF    3136000    // [70][100]      = 7000
#define VNINV_OFF 3143000    // [70] pad 128
#define PSUM_OFF  3143128    // [70][64] = 4480
#define QV_OFF    3147608    // [1024][64] = 65536
#define INVQ_OFF  3213144    // [1024][100] = 102400
#define SIM32_OFF 3315544    // [80][1024][70] = 5734400
#define PW_OFF    9049944    // [1024][70] = 71680
#define PQ4_OFF   9121624    // [4][1024][5][64] = 1310720
#define CLS_OFF   10432344   // [1024]
#define ALN_OFF   10433368   // [1024]
#define PSUMP_OFF 10434392   // [70][25][64] = 112000
#define SSQP_OFF  10546392   // [70][25] pad

#define PQ_ELEMS (NQ*NWAY*64)
#define SIM_STRIDE (NQ*NPAIR)

__device__ __forceinline__ float redsum64(float x){
  #pragma unroll
  for (int o = 1; o < 64; o <<= 1) x += __shfl_xor(x, o, 64);
  return x;
}

// ---------------- kN: per-sample L2(pos) normalize; support -> vptS, query -> invq+qv ----------------
__global__ __launch_bounds__(256) void kN(const float* __restrict__ feat,
                                          float* __restrict__ vptS,
                                          float* __restrict__ invq,
                                          float* __restrict__ qv){
  __shared__ float lds[64*101];
  __shared__ float inv[100];
  int s = blockIdx.x, t = threadIdx.x;
  const float* fp = feat + (size_t)s * 6400;
  #pragma unroll
  for (int i = 0; i < 25; i++){
    int j = t + 256*i;
    int d = j / 100, p = j - d*100;
    lds[d*101 + p] = fp[j];
  }
  __syncthreads();
  if (t < 100){
    float ss = 0.f;
    #pragma unroll
    for (int d = 0; d < 64; d++){ float x = lds[d*101 + t]; ss += x*x; }
    inv[t] = 1.f / fmaxf(sqrtf(ss), 1e-12f);
  }
  __syncthreads();
  if (s < NS){
    #pragma unroll
    for (int i = 0; i < 25; i++){
      int j = t + 256*i;
      int p = j >> 6, d = j & 63;
      vptS[(size_t)s*6400 + j] = lds[d*101 + p] * inv[p];
    }
  } else {
    int q = s - NS;
    if (t < 100) invq[q*100 + t] = inv[t];
    if (t < 64){
      float sum = 0.f;
      for (int p = 0; p < PP; p++) sum += lds[t*101 + p] * inv[p];
      qv[q*64 + t] = sum * 0.01f;
    }
  }
}

// ---------------- kVb: sum 5 shots -> vpt + B2T + MM + psumP + ssqP ----------------
// grid 1750: pair = b/25, chunk jc = b%25 (4 p's x 64 d)
__global__ __launch_bounds__(256) void kVb(const float* __restrict__ vptS,
                                           float* __restrict__ vpt,
                                           float* __restrict__ B2T,
                                           float* __restrict__ MM,
                                           float* __restrict__ psumP,
                                           float* __restrict__ ssqP){
  __shared__ float l2[256];
  __shared__ float wssq[4];
  int b = blockIdx.x;
  int pair = b / 25, jc = b - pair*25;
  int n = pair / PRJ, v = pair - n*PRJ;
  int j0 = jc * 256;
  int t = threadIdx.x;
  int j = j0 + t;
  float s = 0.f;
  #pragma unroll
  for (int k = 0; k < KSHOT; k++){
    int sk = (n*KSHOT + k)*PRJ + v;
    s += vptS[(size_t)sk*6400 + j];
  }
  float val = s * 0.2f;
  vpt[(size_t)pair*6400 + j] = val;
  int p = j >> 6, d = j & 63;
  int plocal = p & 3;
  l2[d*4 + plocal] = val;
  float sq = redsum64(val*val);
  if ((t & 63) == 0) wssq[t >> 6] = sq;
  __syncthreads();
  if (t < 64){
    int p0 = j0 >> 6;
    float4 w4 = make_float4(l2[t*4+0], l2[t*4+1], l2[t*4+2], l2[t*4+3]);
    // B2T[pair][f], f = d*100 + p: contiguous float4 (d = t, p = p0..p0+3)
    *(float4*)(B2T + (size_t)pair*6400 + t*100 + p0) = w4;
    psumP[((size_t)pair*25 + jc)*64 + t] = w4.x + w4.y + w4.z + w4.w;
  }
  if (t >= 128 && t < 132){
    int i = t - 128;
    float m = 0.f;
    #pragma unroll
    for (int dd2 = 0; dd2 < 64; dd2++) m += l2[dd2*4 + i];
    MM[pair*100 + (j0 >> 6) + i] = m * (1.f/64.f);
  }
  if (t == 192)
    ssqP[pair*25 + jc] = wssq[0] + wssq[1] + wssq[2] + wssq[3];
}

// ---------------- kVc2: reduce chunk partials -> psum + vninv ----------------
__global__ __launch_bounds__(64) void kVc2(const float* __restrict__ psumP,
                                           const float* __restrict__ ssqP,
                                           float* __restrict__ psum,
                                           float* __restrict__ vninv){
  int pair = blockIdx.x, l = threadIdx.x;
  float s = 0.f;
  #pragma unroll
  for (int c = 0; c < 25; c++) s += psumP[((size_t)pair*25 + c)*64 + l];
  psum[pair*64 + l] = s;
  float sq = (l < 25) ? ssqP[pair*25 + l] : 0.f;
  float tot = redsum64(sq);
  if (l == 0) vninv[pair] = 1.f / fmaxf(sqrtf(tot), 1e-12f);
}

// ---------------- kS v7: register-tiled GEMM, A+B in LDS, b128 reads ----------------
// grid 640: qg = b&7 (128 q), fg = b>>3 (80 f). 128 thr, thread tile 8q x 9pr.
__global__ __launch_bounds__(128) void kS(const float* __restrict__ feat,
                                          const float* __restrict__ invq,
                                          const float* __restrict__ B2T,
                                          float* __restrict__ sim32){
  __shared__ float A[128*84];     // [q][f], pad 84 -> row shift 20 banks
  __shared__ float Bl[72*84];     // [pr][f]
  int b = blockIdx.x;
  int qg = b & 7, fg = b >> 3;
  int q0 = qg * 128;
  int fbase = fg * KCH;
  int t = threadIdx.x;

  // stage A: 128 q x 80 f = 2560 float4, invq folded in
  for (int i = t; i < 2560; i += 128){
    int q = i / 20, c4 = i - q*20;
    int f0 = fbase + c4*4;
    float4 f4 = *(const float4*)(feat + (size_t)(NS + q0 + q)*6400 + f0);
    const float* iq = invq + (q0 + q)*100;
    int p0 = f0 % 100, p1 = (f0+1) % 100, p2 = (f0+2) % 100, p3 = (f0+3) % 100;
    *(float4*)(A + q*84 + c4*4) =
      make_float4(f4.x*iq[p0], f4.y*iq[p1], f4.z*iq[p2], f4.w*iq[p3]);
  }
  // stage B: 72 rows x 80 f = 1440 float4 (rows >=70 zero)
  for (int i = t; i < 1440; i += 128){
    int pr = i / 20, c4 = i - pr*20;
    float4 v = make_float4(0.f, 0.f, 0.f, 0.f);
    if (pr < NPAIR) v = *(const float4*)(B2T + (size_t)pr*6400 + fbase + c4*4);
    *(float4*)(Bl + pr*84 + c4*4) = v;
  }
  __syncthreads();

  int tr = t & 15, tc = t >> 4;   // tr: q rows {tr+16i}, tc: pr cols {tc*9+j}
  float acc[8][9];
  #pragma unroll
  for (int i = 0; i < 8; i++)
    #pragma unroll
    for (int j = 0; j < 9; j++) acc[i][j] = 0.f;

  #pragma unroll 2
  for (int r = 0; r < KCH; r += 4){
    float4 b4[9];
    #pragma unroll
    for (int j = 0; j < 9; j++)
      b4[j] = *(const float4*)(Bl + (tc*9 + j)*84 + r);
    #pragma unroll
    for (int i = 0; i < 8; i++){
      float4 a4 = *(const float4*)(A + (tr + 16*i)*84 + r);
      #pragma unroll
      for (int j = 0; j < 9; j++)
        acc[i][j] += a4.x*b4[j].x + a4.y*b4[j].y + a4.z*b4[j].z + a4.w*b4[j].w;
    }
  }

  #pragma unroll
  for (int i = 0; i < 8; i++){
    int q = q0 + tr + 16*i;
    #pragma unroll
    for (int j = 0; j < 9; j++){
      int pr = tc*9 + j;
      if (pr < NPAIR) sim32[(size_t)fg*SIM_STRIDE + q*NPAIR + pr] = acc[i][j];
    }
  }
}

// ---------------- kM: sum 80 f-chunk partials + per-(q,n) softmax over 14 views ----------------
__global__ __launch_bounds__(256) void kM(const float* __restrict__ sim32,
                                          const float* __restrict__ vninv,
                                          const float* __restrict__ temp,
                                          float* __restrict__ pw){
  int t = blockIdx.x*256 + threadIdx.x;
  if (t >= NQ*NWAY) return;
  int q = t / NWAY, n = t - q*NWAY;
  float invT = 1.f / (temp[0] + 1e-6f);
  float s[PRJ];
  #pragma unroll
  for (int v = 0; v < PRJ; v++) s[v] = 0.f;
  for (int c = 0; c < FGROUPS; c++){
    const float* sp = sim32 + (size_t)c*SIM_STRIDE + q*NPAIR + n*PRJ;
    #pragma unroll
    for (int v = 0; v < PRJ; v++) s[v] += sp[v];
  }
  float m = -3.4e38f;
  #pragma unroll
  for (int v = 0; v < PRJ; v++){
    s[v] = s[v] * vninv[n*PRJ + v] * invT;
    m = fmaxf(m, s[v]);
  }
  float sum = 0.f;
  #pragma unroll
  for (int v = 0; v < PRJ; v++){ s[v] = expf(s[v] - m); sum += s[v]; }
  float rs = 1.f / sum;
  #pragma unroll
  for (int v = 0; v < PRJ; v++) pw[q*NPAIR + n*PRJ + v] = s[v] * rs;
}

// ---------------- kP: p-split 4x, sg computed inline, partial outputs ----------------
__global__ __launch_bounds__(256) void kP(const float* __restrict__ vpt,
                                          const float* __restrict__ pw,
                                          const float* __restrict__ MM,
                                          float* __restrict__ pq4){
  __shared__ float sgl[16][PCHUNK];
  int b = blockIdx.x;
  int n  = b / 256;
  int r  = b - n*256;
  int qb = r >> 2;
  int s  = r & 3;
  int p0 = s * PCHUNK;
  int t = threadIdx.x, w = t >> 6, l = t & 63;
  int q0 = qb*16 + w*4;

  float wq[4][PRJ];
  #pragma unroll
  for (int j = 0; j < 4; j++)
    #pragma unroll
    for (int v = 0; v < PRJ; v++)
      wq[j][v] = pw[(q0+j)*NPAIR + n*PRJ + v];

  if (l < PCHUNK){
    #pragma unroll
    for (int j = 0; j < 4; j++){
      float ssg = 0.f;
      #pragma unroll
      for (int v = 0; v < PRJ; v++)
        ssg += wq[j][v] * MM[(n*PRJ + v)*100 + p0 + l];
      sgl[w*4 + j][l] = 1.f / (1.f + expf(-ssg));
    }
  }
  __syncthreads();

  float acc[4] = {0.f, 0.f, 0.f, 0.f};
  const float* vb = vpt + (size_t)n * PRJ * 6400;
  for (int pl = 0; pl < PCHUNK; pl++){
    int p = p0 + pl;
    float vv[PRJ];
    #pragma unroll
    for (int v = 0; v < PRJ; v++) vv[v] = vb[v*6400 + p*64 + l];
    #pragma unroll
    for (int j = 0; j < 4; j++){
      float dot = 0.f;
      #pragma unroll
      for (int v = 0; v < PRJ; v++) dot += wq[j][v] * vv[v];
      acc[j] += sgl[w*4 + j][pl] * dot;
    }
  }
  #pragma unroll
  for (int j = 0; j < 4; j++)
    pq4[(size_t)s*PQ_ELEMS + ((q0+j)*NWAY + n)*64 + l] = acc[j];
}

// ---------------- kF: 5 waves per query, wave = n; pq4-sum and base fused in ----------------
__global__ __launch_bounds__(320) void kF(const float* __restrict__ qv,
                                          const float* __restrict__ pq4,
                                          const float* __restrict__ psum,
                                          const float* __restrict__ Wq,
                                          const float* __restrict__ bq,
                                          const float* __restrict__ Wk,
                                          const float* __restrict__ bk,
                                          const float* __restrict__ gate,
                                          const int*   __restrict__ label,
                                          float* __restrict__ pred,
                                          float* __restrict__ cls,
                                          float* __restrict__ aln){
  __shared__ float qvl[64];
  __shared__ float qp[16];
  __shared__ float scn[NWAY], cosn[NWAY], c2n[NWAY];
  __shared__ float dl5[NWAY][64];
  int q = blockIdx.x, t = threadIdx.x;
  int w = t >> 6, l = t & 63;      // w = n

  float qvv = qv[q*64 + l];
  float qss = redsum64(qvv*qvv);
  float qn8 = fmaxf(sqrtf(qss), 1e-8f);
  if (w == 0) qvl[l] = qvv;
  __syncthreads();
  if (w == 0 && l < 16){
    float s = bq[l];
    #pragma unroll
    for (int d = 0; d < 64; d++) s += qvl[d] * Wq[d*16 + l];
    qp[l] = s;
  }
  __syncthreads();

  float wkq = 0.f;
  #pragma unroll
  for (int e = 0; e < 16; e++) wkq += Wk[l*16 + e] * qp[e];
  float qpb = 0.f;
  #pragma unroll
  for (int e = 0; e < 16; e++) qpb += qp[e] * bk[e];

  size_t idx = (size_t)(q*NWAY + w)*64 + l;
  float x = pq4[idx] + pq4[PQ_ELEMS + idx] + pq4[2*PQ_ELEMS + idx] + pq4[3*PQ_ELEMS + idx];

  float dq = redsum64(qvv * x);
  float ps = redsum64(x * x);
  float cosw = dq / (qn8 * fmaxf(sqrtf(ps), 1e-8f));
  float sd = redsum64(x * wkq);
  float scw = (sd + qpb) * 0.25f;
  if (l == 0){ scn[w] = scw; cosn[w] = cosw; }
  __syncthreads();

  float am = scn[0];
  #pragma unroll
  for (int n = 1; n < NWAY; n++) am = fmaxf(am, scn[n]);
  float asum = 0.f;
  #pragma unroll
  for (int n = 0; n < NWAY; n++) asum += expf(scn[n] - am);
  float attw = expf(scw - am) / asum;

  float g0 = gate[0], g1 = gate[1], g2 = gate[2];
  float gm = fmaxf(fmaxf(g0, g1), g2);
  float e0 = expf(g0 - gm), e1 = expf(g1 - gm), e2 = expf(g2 - gm);
  float gs = 1.f / (e0 + e1 + e2);
  float b0 = (e0 + e1 + e2) * gs;
  float b1 = (e1 + e2) * gs;
  float b2 = e2 * gs;

  float bs = 0.f;
  #pragma unroll
  for (int v = 0; v < PRJ; v++) bs += psum[(w*PRJ + v)*64 + l];
  bs *= (1.f/1400.f);

  float f  = x * attw;
  float dd = fabsf(f - bs);
  dl5[w][l] = dd;
  int rank = 0;
  #pragma unroll 8
  for (int j = 0; j < 64; j++){
    float dj = dl5[w][j];
    rank += (dj > dd) || (dj == dd && j < l);
  }
  float cw = (rank < 16) ? b0 : (rank < 32) ? b1 : (rank < 48) ? b2 : 0.f;
  float gl = f * cw;
  float gss = redsum64(gl * gl);
  float num = redsum64(qvv * gl);
  float c2w = num / (qn8 * fmaxf(sqrtf(gss), 1e-12f));
  if (l == 0) c2n[w] = c2w;
  __syncthreads();

  float mx = c2n[0];
  #pragma unroll
  for (int n = 1; n < NWAY; n++) mx = fmaxf(mx, c2n[n]);
  float psum2 = 0.f;
  #pragma unroll
  for (int n = 0; n < NWAY; n++) psum2 += expf(c2n[n] - mx);
  if (l == 0) pred[q*NWAY + w] = expf(c2w - mx) / psum2;

  if (t == 0){
    int lab = label[q];
    float lm = LAMDA * mx;
    float lsum = 0.f;
    #pragma unroll
    for (int n = 0; n < NWAY; n++) lsum += expf(LAMDA * c2n[n] - lm);
    float c2l = c2n[lab], cosl = cosn[lab];
    float clsv = (lm + logf(lsum)) - LAMDA * c2l;
    float sum5 = 0.f, minn = 3.4e38f;
    #pragma unroll
    for (int n = 0; n < NWAY; n++){
      sum5 += cosn[n];
      if (n != lab) minn = fminf(minn, cosn[n]);
    }
    float hn = (sum5 - cosl - minn) * (1.f/3.f);
    float al = fmaxf(hn - cosl + MARGIN, 0.f);
    cls[q] = clsv; aln[q] = al;
  }
}

// ---------------- kL: loss reduction ----------------
__global__ __launch_bounds__(256) void kL(const float* __restrict__ cls,
                                          const float* __restrict__ aln,
                                          float* __restrict__ out){
  __shared__ float r1[256], r2[256];
  int t = threadIdx.x;
  float s1 = 0.f, s2 = 0.f;
  for (int i = t; i < NQ; i += 256){ s1 += cls[i]; s2 += aln[i]; }
  r1[t] = s1; r2[t] = s2;
  __syncthreads();
  for (int o = 128; o > 0; o >>= 1){
    if (t < o){ r1[t] += r1[t + o]; r2[t] += r2[t + o]; }
    __syncthreads();
  }
  if (t == 0)
    out[NQ*NWAY] = r1[0]*(1.f/NQ) + 0.3f*(r2[0]*(1.f/NQ));
}

extern "C" void kernel_launch(void* const* d_in, const int* in_sizes, int n_in,
                              void* d_out, int out_size, void* d_ws, size_t ws_size,
                              hipStream_t stream){
  const float* feat = (const float*)d_in[0];
  const float* temp = (const float*)d_in[1];
  const float* gate = (const float*)d_in[2];
  const float* Wq   = (const float*)d_in[3];
  const float* bq   = (const float*)d_in[4];
  const float* Wk   = (const float*)d_in[5];
  const float* bk   = (const float*)d_in[6];
  const int*   lab  = (const int*)d_in[7];
  float* out = (float*)d_out;
  float* ws  = (float*)d_ws;

  float* vpt   = ws + VPT_OFF;
  float* vptS  = ws + VPTS_OFF;
  float* B2T   = ws + B2T_OFF;
  float* MMp   = ws + MM_OFF;
  float* vninv = ws + VNINV_OFF;
  float* psum  = ws + PSUM_OFF;
  float* qv    = ws + QV_OFF;
  float* invq  = ws + INVQ_OFF;
  float* sim32 = ws + SIM32_OFF;
  float* pw    = ws + PW_OFF;
  float* pq4   = ws + PQ4_OFF;
  float* cls   = ws + CLS_OFF;
  float* aln   = ws + ALN_OFF;
  float* psumP = ws + PSUMP_OFF;
  float* ssqP  = ws + SSQP_OFF;

  hipLaunchKernelGGL(kN, dim3(NS + NQ), dim3(256), 0, stream, feat, vptS, invq, qv);
  hipLaunchKernelGGL(kVb, dim3(NPAIR*25), dim3(256), 0, stream, vptS, vpt, B2T, MMp, psumP, ssqP);
  hipLaunchKernelGGL(kVc2, dim3(NPAIR), dim3(64), 0, stream, psumP, ssqP, psum, vninv);
  hipLaunchKernelGGL(kS, dim3(8*FGROUPS), dim3(128), 0, stream, feat, invq, B2T, sim32);
  hipLaunchKernelGGL(kM, dim3((NQ*NWAY + 255)/256), dim3(256), 0, stream, sim32, vninv, temp, pw);
  hipLaunchKernelGGL(kP, dim3(NWAY*256), dim3(256), 0, stream, vpt, pw, MMp, pq4);
  hipLaunchKernelGGL(kF, dim3(NQ), dim3(320), 0, stream, qv, pq4, psum, Wq, bq, Wk, bk, gate, lab, out, cls, aln);
  hipLaunchKernelGGL(kL, dim3(1), dim3(256), 0, stream, cls, aln, out);
}

// Round 12
// 128.881 us; speedup vs baseline: 1.3046x; 1.3046x over previous
//
#include <hip/hip_runtime.h>
#include <math.h>

#define NWAY 5
#define KSHOT 5
#define PRJ 14
#define DD 64
#define PP 100
#define NQ 1024
#define NS 350
#define NPAIR 70
#define LAMDA 32.0f
#define MARGIN 0.3f
#define PCHUNK 25
#define FGROUPS 64
#define KCH 100

// ---- workspace layout (floats), ~37.6 MB ----
#define VPT_OFF   0          // [70][100][64]  = 448000  ([p][d])
#define VPTS_OFF  448000     // [350][6400]    = 2240000
#define B2T_OFF   2688000    // [70][6400]     = 448000  (f = d*100+p contiguous)
#define MM_OFF    3136000    // [70][100]      = 7000
#define VNINV_OFF 3143000    // [70] pad 128
#define PSUM_OFF  3143128    // [70][64] = 4480
#define QV_OFF    3147608    // [1024][64] = 65536
#define INVQ_OFF  3213144    // [1024][100] = 102400
#define SIM32_OFF 3315544    // [64][1024][70] = 4587520
#define PW_OFF    7903064    // [1024][70] = 71680
#define PQ4_OFF   7974744    // [4][1024][5][64] = 1310720
#define CLS_OFF   9285464    // [1024]
#define ALN_OFF   9286488    // [1024]
#define PSUMP_OFF 9287512    // [70][25][64] = 112000
#define SSQP_OFF  9399512    // [70][25] pad

#define PQ_ELEMS (NQ*NWAY*64)
#define SIM_STRIDE (NQ*NPAIR)

__device__ __forceinline__ float redsum64(float x){
  #pragma unroll
  for (int o = 1; o < 64; o <<= 1) x += __shfl_xor(x, o, 64);
  return x;
}

// ---------------- kN: per-sample L2(pos) normalize; support -> vptS, query -> invq+qv ----------------
__global__ __launch_bounds__(256) void kN(const float* __restrict__ feat,
                                          float* __restrict__ vptS,
                                          float* __restrict__ invq,
                                          float* __restrict__ qv){
  __shared__ float lds[64*101];
  __shared__ float inv[100];
  int s = blockIdx.x, t = threadIdx.x;
  const float* fp = feat + (size_t)s * 6400;
  #pragma unroll
  for (int i = 0; i < 25; i++){
    int j = t + 256*i;
    int d = j / 100, p = j - d*100;
    lds[d*101 + p] = fp[j];
  }
  __syncthreads();
  if (t < 100){
    float ss = 0.f;
    #pragma unroll
    for (int d = 0; d < 64; d++){ float x = lds[d*101 + t]; ss += x*x; }
    inv[t] = 1.f / fmaxf(sqrtf(ss), 1e-12f);
  }
  __syncthreads();
  if (s < NS){
    #pragma unroll
    for (int i = 0; i < 25; i++){
      int j = t + 256*i;
      int p = j >> 6, d = j & 63;
      vptS[(size_t)s*6400 + j] = lds[d*101 + p] * inv[p];
    }
  } else {
    int q = s - NS;
    if (t < 100) invq[q*100 + t] = inv[t];
    if (t < 64){
      float sum = 0.f;
      for (int p = 0; p < PP; p++) sum += lds[t*101 + p] * inv[p];
      qv[q*64 + t] = sum * 0.01f;
    }
  }
}

// ---------------- kVb: sum 5 shots -> vpt + B2T + MM + psumP + ssqP ----------------
__global__ __launch_bounds__(256) void kVb(const float* __restrict__ vptS,
                                           float* __restrict__ vpt,
                                           float* __restrict__ B2T,
                                           float* __restrict__ MM,
                                           float* __restrict__ psumP,
                                           float* __restrict__ ssqP){
  __shared__ float l2[256];
  __shared__ float wssq[4];
  int b = blockIdx.x;
  int pair = b / 25, jc = b - pair*25;
  int n = pair / PRJ, v = pair - n*PRJ;
  int j0 = jc * 256;
  int t = threadIdx.x;
  int j = j0 + t;
  float s = 0.f;
  #pragma unroll
  for (int k = 0; k < KSHOT; k++){
    int sk = (n*KSHOT + k)*PRJ + v;
    s += vptS[(size_t)sk*6400 + j];
  }
  float val = s * 0.2f;
  vpt[(size_t)pair*6400 + j] = val;
  int p = j >> 6, d = j & 63;
  int plocal = p & 3;
  l2[d*4 + plocal] = val;
  float sq = redsum64(val*val);
  if ((t & 63) == 0) wssq[t >> 6] = sq;
  __syncthreads();
  if (t < 64){
    int p0 = j0 >> 6;
    float4 w4 = make_float4(l2[t*4+0], l2[t*4+1], l2[t*4+2], l2[t*4+3]);
    *(float4*)(B2T + (size_t)pair*6400 + t*100 + p0) = w4;
    psumP[((size_t)pair*25 + jc)*64 + t] = w4.x + w4.y + w4.z + w4.w;
  }
  if (t >= 128 && t < 132){
    int i = t - 128;
    float m = 0.f;
    #pragma unroll
    for (int dd2 = 0; dd2 < 64; dd2++) m += l2[dd2*4 + i];
    MM[pair*100 + (j0 >> 6) + i] = m * (1.f/64.f);
  }
  if (t == 192)
    ssqP[pair*25 + jc] = wssq[0] + wssq[1] + wssq[2] + wssq[3];
}

// ---------------- kVc2: reduce chunk partials -> psum + vninv ----------------
__global__ __launch_bounds__(64) void kVc2(const float* __restrict__ psumP,
                                           const float* __restrict__ ssqP,
                                           float* __restrict__ psum,
                                           float* __restrict__ vninv){
  int pair = blockIdx.x, l = threadIdx.x;
  float s = 0.f;
  #pragma unroll
  for (int c = 0; c < 25; c++) s += psumP[((size_t)pair*25 + c)*64 + l];
  psum[pair*64 + l] = s;
  float sq = (l < 25) ? ssqP[pair*25 + l] : 0.f;
  float tot = redsum64(sq);
  if (l == 0) vninv[pair] = 1.f / fmaxf(sqrtf(tot), 1e-12f);
}

// ---------------- kS v8: lane=query, B in LDS (uniform broadcast), f-split 64 ----------------
// grid 1024: qg = b&15 (64 q), fg = b>>4 (100 f = d-plane fg). 4 waves x 18 pairs.
__global__ __launch_bounds__(256) void kS(const float* __restrict__ feat,
                                          const float* __restrict__ invq,
                                          const float* __restrict__ B2T,
                                          float* __restrict__ sim32){
  __shared__ float A[64*104];     // [q][f] pad 104 (16B-aligned rows)
  __shared__ float Bl[72*104];    // [pr][f], rows 70/71 zero
  int b = blockIdx.x;
  int qg = b & 15, fg = b >> 4;
  int q0 = qg * 64;
  int fbase = fg * KCH;           // multiple of 100 -> whole chunk is d-plane fg, p = c4*4+k
  int t = threadIdx.x;
  int l = t & 63;
  int wu = __builtin_amdgcn_readfirstlane(t >> 6);
  int pr0 = wu * 18;              // waves: 18,18,18,16 real pairs (72 padded)

  // stage A: 64 q x 25 float4, invq folded (p = c4*4..+3 since fbase%100==0)
  for (int i = t; i < 1600; i += 256){
    int q = i / 25, c4 = i - q*25;
    float4 f4 = *(const float4*)(feat + (size_t)(NS + q0 + q)*6400 + fbase + c4*4);
    float4 v4 = *(const float4*)(invq + (q0 + q)*100 + c4*4);
    *(float4*)(A + q*104 + c4*4) =
      make_float4(f4.x*v4.x, f4.y*v4.y, f4.z*v4.z, f4.w*v4.w);
  }
  // stage B: 72 rows x 25 float4 (rows >= 70 zero)
  for (int i = t; i < 1800; i += 256){
    int pr = i / 25, c4 = i - pr*25;
    float4 v = make_float4(0.f, 0.f, 0.f, 0.f);
    if (pr < NPAIR) v = *(const float4*)(B2T + (size_t)pr*6400 + fbase + c4*4);
    *(float4*)(Bl + pr*104 + c4*4) = v;
  }
  __syncthreads();

  float acc[18];
  #pragma unroll
  for (int j = 0; j < 18; j++) acc[j] = 0.f;

  const float* Al = A + l*104;
  const float* Bw = Bl + pr0*104;
  for (int r = 0; r < KCH; r += 4){
    float4 a4 = *(const float4*)(Al + r);
    #pragma unroll
    for (int j = 0; j < 18; j++){
      float4 b4 = *(const float4*)(Bw + j*104 + r);   // wave-uniform -> broadcast
      acc[j] += a4.x*b4.x + a4.y*b4.y + a4.z*b4.z + a4.w*b4.w;
    }
  }

  int qq = q0 + l;
  #pragma unroll
  for (int j = 0; j < 18; j++){
    int pr = pr0 + j;
    if (pr < NPAIR) sim32[(size_t)fg*SIM_STRIDE + qq*NPAIR + pr] = acc[j];
  }
}

// ---------------- kM: sum 64 f-chunk partials + per-(q,n) softmax over 14 views ----------------
__global__ __launch_bounds__(256) void kM(const float* __restrict__ sim32,
                                          const float* __restrict__ vninv,
                                          const float* __restrict__ temp,
                                          float* __restrict__ pw){
  int t = blockIdx.x*256 + threadIdx.x;
  if (t >= NQ*NWAY) return;
  int q = t / NWAY, n = t - q*NWAY;
  float invT = 1.f / (temp[0] + 1e-6f);
  float s[PRJ];
  #pragma unroll
  for (int v = 0; v < PRJ; v++) s[v] = 0.f;
  for (int c = 0; c < FGROUPS; c++){
    const float* sp = sim32 + (size_t)c*SIM_STRIDE + q*NPAIR + n*PRJ;
    #pragma unroll
    for (int v = 0; v < PRJ; v++) s[v] += sp[v];
  }
  float m = -3.4e38f;
  #pragma unroll
  for (int v = 0; v < PRJ; v++){
    s[v] = s[v] * vninv[n*PRJ + v] * invT;
    m = fmaxf(m, s[v]);
  }
  float sum = 0.f;
  #pragma unroll
  for (int v = 0; v < PRJ; v++){ s[v] = expf(s[v] - m); sum += s[v]; }
  float rs = 1.f / sum;
  #pragma unroll
  for (int v = 0; v < PRJ; v++) pw[q*NPAIR + n*PRJ + v] = s[v] * rs;
}

// ---------------- kP: p-split 4x, sg computed inline, partial outputs ----------------
__global__ __launch_bounds__(256) void kP(const float* __restrict__ vpt,
                                          const float* __restrict__ pw,
                                          const float* __restrict__ MM,
                                          float* __restrict__ pq4){
  __shared__ float sgl[16][PCHUNK];
  int b = blockIdx.x;
  int n  = b / 256;
  int r  = b - n*256;
  int qb = r >> 2;
  int s  = r & 3;
  int p0 = s * PCHUNK;
  int t = threadIdx.x, w = t >> 6, l = t & 63;
  int q0 = qb*16 + w*4;

  float wq[4][PRJ];
  #pragma unroll
  for (int j = 0; j < 4; j++)
    #pragma unroll
    for (int v = 0; v < PRJ; v++)
      wq[j][v] = pw[(q0+j)*NPAIR + n*PRJ + v];

  if (l < PCHUNK){
    #pragma unroll
    for (int j = 0; j < 4; j++){
      float ssg = 0.f;
      #pragma unroll
      for (int v = 0; v < PRJ; v++)
        ssg += wq[j][v] * MM[(n*PRJ + v)*100 + p0 + l];
      sgl[w*4 + j][l] = 1.f / (1.f + expf(-ssg));
    }
  }
  __syncthreads();

  float acc[4] = {0.f, 0.f, 0.f, 0.f};
  const float* vb = vpt + (size_t)n * PRJ * 6400;
  for (int pl = 0; pl < PCHUNK; pl++){
    int p = p0 + pl;
    float vv[PRJ];
    #pragma unroll
    for (int v = 0; v < PRJ; v++) vv[v] = vb[v*6400 + p*64 + l];
    #pragma unroll
    for (int j = 0; j < 4; j++){
      float dot = 0.f;
      #pragma unroll
      for (int v = 0; v < PRJ; v++) dot += wq[j][v] * vv[v];
      acc[j] += sgl[w*4 + j][pl] * dot;
    }
  }
  #pragma unroll
  for (int j = 0; j < 4; j++)
    pq4[(size_t)s*PQ_ELEMS + ((q0+j)*NWAY + n)*64 + l] = acc[j];
}

// ---------------- kF: 5 waves per query, wave = n; pq4-sum and base fused in ----------------
__global__ __launch_bounds__(320) void kF(const float* __restrict__ qv,
                                          const float* __restrict__ pq4,
                                          const float* __restrict__ psum,
                                          const float* __restrict__ Wq,
                                          const float* __restrict__ bq,
                                          const float* __restrict__ Wk,
                                          const float* __restrict__ bk,
                                          const float* __restrict__ gate,
                                          const int*   __restrict__ label,
                                          float* __restrict__ pred,
                                          float* __restrict__ cls,
                                          float* __restrict__ aln){
  __shared__ float qvl[64];
  __shared__ float qp[16];
  __shared__ float scn[NWAY], cosn[NWAY], c2n[NWAY];
  __shared__ float dl5[NWAY][64];
  int q = blockIdx.x, t = threadIdx.x;
  int w = t >> 6, l = t & 63;      // w = n

  float qvv = qv[q*64 + l];
  float qss = redsum64(qvv*qvv);
  float qn8 = fmaxf(sqrtf(qss), 1e-8f);
  if (w == 0) qvl[l] = qvv;
  __syncthreads();
  if (w == 0 && l < 16){
    float s = bq[l];
    #pragma unroll
    for (int d = 0; d < 64; d++) s += qvl[d] * Wq[d*16 + l];
    qp[l] = s;
  }
  __syncthreads();

  float wkq = 0.f;
  #pragma unroll
  for (int e = 0; e < 16; e++) wkq += Wk[l*16 + e] * qp[e];
  float qpb = 0.f;
  #pragma unroll
  for (int e = 0; e < 16; e++) qpb += qp[e] * bk[e];

  size_t idx = (size_t)(q*NWAY + w)*64 + l;
  float x = pq4[idx] + pq4[PQ_ELEMS + idx] + pq4[2*PQ_ELEMS + idx] + pq4[3*PQ_ELEMS + idx];

  float dq = redsum64(qvv * x);
  float ps = redsum64(x * x);
  float cosw = dq / (qn8 * fmaxf(sqrtf(ps), 1e-8f));
  float sd = redsum64(x * wkq);
  float scw = (sd + qpb) * 0.25f;
  if (l == 0){ scn[w] = scw; cosn[w] = cosw; }
  __syncthreads();

  float am = scn[0];
  #pragma unroll
  for (int n = 1; n < NWAY; n++) am = fmaxf(am, scn[n]);
  float asum = 0.f;
  #pragma unroll
  for (int n = 0; n < NWAY; n++) asum += expf(scn[n] - am);
  float attw = expf(scw - am) / asum;

  float g0 = gate[0], g1 = gate[1], g2 = gate[2];
  float gm = fmaxf(fmaxf(g0, g1), g2);
  float e0 = expf(g0 - gm), e1 = expf(g1 - gm), e2 = expf(g2 - gm);
  float gs = 1.f / (e0 + e1 + e2);
  float b0 = (e0 + e1 + e2) * gs;
  float b1 = (e1 + e2) * gs;
  float b2 = e2 * gs;

  float bs = 0.f;
  #pragma unroll
  for (int v = 0; v < PRJ; v++) bs += psum[(w*PRJ + v)*64 + l];
  bs *= (1.f/1400.f);

  float f  = x * attw;
  float dd = fabsf(f - bs);
  dl5[w][l] = dd;
  int rank = 0;
  #pragma unroll 8
  for (int j = 0; j < 64; j++){
    float dj = dl5[w][j];
    rank += (dj > dd) || (dj == dd && j < l);
  }
  float cw = (rank < 16) ? b0 : (rank < 32) ? b1 : (rank < 48) ? b2 : 0.f;
  float gl = f * cw;
  float gss = redsum64(gl * gl);
  float num = redsum64(qvv * gl);
  float c2w = num / (qn8 * fmaxf(sqrtf(gss), 1e-12f));
  if (l == 0) c2n[w] = c2w;
  __syncthreads();

  float mx = c2n[0];
  #pragma unroll
  for (int n = 1; n < NWAY; n++) mx = fmaxf(mx, c2n[n]);
  float psum2 = 0.f;
  #pragma unroll
  for (int n = 0; n < NWAY; n++) psum2 += expf(c2n[n] - mx);
  if (l == 0) pred[q*NWAY + w] = expf(c2w - mx) / psum2;

  if (t == 0){
    int lab = label[q];
    float lm = LAMDA * mx;
    float lsum = 0.f;
    #pragma unroll
    for (int n = 0; n < NWAY; n++) lsum += expf(LAMDA * c2n[n] - lm);
    float c2l = c2n[lab], cosl = cosn[lab];
    float clsv = (lm + logf(lsum)) - LAMDA * c2l;
    float sum5 = 0.f, minn = 3.4e38f;
    #pragma unroll
    for (int n = 0; n < NWAY; n++){
      sum5 += cosn[n];
      if (n != lab) minn = fminf(minn, cosn[n]);
    }
    float hn = (sum5 - cosl - minn) * (1.f/3.f);
    float al = fmaxf(hn - cosl + MARGIN, 0.f);
    cls[q] = clsv; aln[q] = al;
  }
}

// ---------------- kL: loss reduction ----------------
__global__ __launch_bounds__(256) void kL(const float* __restrict__ cls,
                                          const float* __restrict__ aln,
                                          float* __restrict__ out){
  __shared__ float r1[256], r2[256];
  int t = threadIdx.x;
  float s1 = 0.f, s2 = 0.f;
  for (int i = t; i < NQ; i += 256){ s1 += cls[i]; s2 += aln[i]; }
  r1[t] = s1; r2[t] = s2;
  __syncthreads();
  for (int o = 128; o > 0; o >>= 1){
    if (t < o){ r1[t] += r1[t + o]; r2[t] += r2[t + o]; }
    __syncthreads();
  }
  if (t == 0)
    out[NQ*NWAY] = r1[0]*(1.f/NQ) + 0.3f*(r2[0]*(1.f/NQ));
}

extern "C" void kernel_launch(void* const* d_in, const int* in_sizes, int n_in,
                              void* d_out, int out_size, void* d_ws, size_t ws_size,
                              hipStream_t stream){
  const float* feat = (const float*)d_in[0];
  const float* temp = (const float*)d_in[1];
  const float* gate = (const float*)d_in[2];
  const float* Wq   = (const float*)d_in[3];
  const float* bq   = (const float*)d_in[4];
  const float* Wk   = (const float*)d_in[5];
  const float* bk   = (const float*)d_in[6];
  const int*   lab  = (const int*)d_in[7];
  float* out = (float*)d_out;
  float* ws  = (float*)d_ws;

  float* vpt   = ws + VPT_OFF;
  float* vptS  = ws + VPTS_OFF;
  float* B2T   = ws + B2T_OFF;
  float* MMp   = ws + MM_OFF;
  float* vninv = ws + VNINV_OFF;
  float* psum  = ws + PSUM_OFF;
  float* qv    = ws + QV_OFF;
  float* invq  = ws + INVQ_OFF;
  float* sim32 = ws + SIM32_OFF;
  float* pw    = ws + PW_OFF;
  float* pq4   = ws + PQ4_OFF;
  float* cls   = ws + CLS_OFF;
  float* aln   = ws + ALN_OFF;
  float* psumP = ws + PSUMP_OFF;
  float* ssqP  = ws + SSQP_OFF;

  hipLaunchKernelGGL(kN, dim3(NS + NQ), dim3(256), 0, stream, feat, vptS, invq, qv);
  hipLaunchKernelGGL(kVb, dim3(NPAIR*25), dim3(256), 0, stream, vptS, vpt, B2T, MMp, psumP, ssqP);
  hipLaunchKernelGGL(kVc2, dim3(NPAIR), dim3(64), 0, stream, psumP, ssqP, psum, vninv);
  hipLaunchKernelGGL(kS, dim3(16*FGROUPS), dim3(256), 0, stream, feat, invq, B2T, sim32);
  hipLaunchKernelGGL(kM, dim3((NQ*NWAY + 255)/256), dim3(256), 0, stream, sim32, vninv, temp, pw);
  hipLaunchKernelGGL(kP, dim3(NWAY*256), dim3(256), 0, stream, vpt, pw, MMp, pq4);
  hipLaunchKernelGGL(kF, dim3(NQ), dim3(320), 0, stream, qv, pq4, psum, Wq, bq, Wk, bk, gate, lab, out, cls, aln);
  hipLaunchKernelGGL(kL, dim3(1), dim3(256), 0, stream, cls, aln, out);
}

// Round 13
// 123.643 us; speedup vs baseline: 1.3598x; 1.0424x over previous
//
#include <hip/hip_runtime.h>
#include <math.h>

#define NWAY 5
#define KSHOT 5
#define PRJ 14
#define DD 64
#define PP 100
#define NQ 1024
#define NS 350
#define NPAIR 70
#define LAMDA 32.0f
#define MARGIN 0.3f
#define PCHUNK 25
#define FGROUPS 64

// ---- workspace layout (floats) ----
#define VPT_OFF   0          // [70][100][64]  = 448000  ([p][d])
#define VPTS_OFF  448000     // [350][6400]    = 2240000
#define B2T_OFF   2688000    // bf16 [70][6400] = 224000 floats worth
#define MM_OFF    3136000    // [70][100]      = 7000
#define VNINV_OFF 3143000    // [70] pad 128
#define PSUM_OFF  3143128    // [70][64] = 4480
#define QV_OFF    3147608    // [1024][64] = 65536
#define INVQ_OFF  3213144    // [1024][100] = 102400
#define SIM32_OFF 3315544    // [64][1024][70] = 4587520
#define PW_OFF    7903064    // [1024][70] = 71680
#define PQ4_OFF   7974744    // [4][1024][5][64] = 1310720
#define CLS_OFF   9285464    // [1024]
#define ALN_OFF   9286488    // [1024]
#define PSUMP_OFF 9287512    // [70][25][64] = 112000
#define SSQP_OFF  9399512    // [70][25] pad

#define PQ_ELEMS (NQ*NWAY*64)
#define SIM_STRIDE (NQ*NPAIR)

__device__ __forceinline__ float redsum64(float x){
  #pragma unroll
  for (int o = 1; o < 64; o <<= 1) x += __shfl_xor(x, o, 64);
  return x;
}

// f32 -> bf16 (RNE) bit pack
__device__ __forceinline__ unsigned short bfr(float x){
  unsigned int u = __float_as_uint(x);
  unsigned int r = (u + 0x7FFFu + ((u >> 16) & 1u)) >> 16;
  return (unsigned short)r;
}
// unpack packed 2xbf16 (u32) -> f32
__device__ __forceinline__ float blo(unsigned int w){ return __uint_as_float(w << 16); }
__device__ __forceinline__ float bhi(unsigned int w){ return __uint_as_float(w & 0xFFFF0000u); }

// ---------------- kN: per-sample L2(pos) normalize; support -> vptS, query -> invq+qv ----------------
__global__ __launch_bounds__(256) void kN(const float* __restrict__ feat,
                                          float* __restrict__ vptS,
                                          float* __restrict__ invq,
                                          float* __restrict__ qv){
  __shared__ float lds[64*101];
  __shared__ float inv[100];
  int s = blockIdx.x, t = threadIdx.x;
  const float* fp = feat + (size_t)s * 6400;
  #pragma unroll
  for (int i = 0; i < 25; i++){
    int j = t + 256*i;
    int d = j / 100, p = j - d*100;
    lds[d*101 + p] = fp[j];
  }
  __syncthreads();
  if (t < 100){
    float ss = 0.f;
    #pragma unroll
    for (int d = 0; d < 64; d++){ float x = lds[d*101 + t]; ss += x*x; }
    inv[t] = 1.f / fmaxf(sqrtf(ss), 1e-12f);
  }
  __syncthreads();
  if (s < NS){
    #pragma unroll
    for (int i = 0; i < 25; i++){
      int j = t + 256*i;
      int p = j >> 6, d = j & 63;
      vptS[(size_t)s*6400 + j] = lds[d*101 + p] * inv[p];
    }
  } else {
    int q = s - NS;
    if (t < 100) invq[q*100 + t] = inv[t];
    if (t < 64){
      float sum = 0.f;
      for (int p = 0; p < PP; p++) sum += lds[t*101 + p] * inv[p];
      qv[q*64 + t] = sum * 0.01f;
    }
  }
}

// ---------------- kVb: sum 5 shots -> vpt + B2T(bf16) + MM + psumP + ssqP ----------------
__global__ __launch_bounds__(256) void kVb(const float* __restrict__ vptS,
                                           float* __restrict__ vpt,
                                           unsigned short* __restrict__ B2T,
                                           float* __restrict__ MM,
                                           float* __restrict__ psumP,
                                           float* __restrict__ ssqP){
  __shared__ float l2[256];
  __shared__ float wssq[4];
  int b = blockIdx.x;
  int pair = b / 25, jc = b - pair*25;
  int n = pair / PRJ, v = pair - n*PRJ;
  int j0 = jc * 256;
  int t = threadIdx.x;
  int j = j0 + t;
  float s = 0.f;
  #pragma unroll
  for (int k = 0; k < KSHOT; k++){
    int sk = (n*KSHOT + k)*PRJ + v;
    s += vptS[(size_t)sk*6400 + j];
  }
  float val = s * 0.2f;
  vpt[(size_t)pair*6400 + j] = val;
  int p = j >> 6, d = j & 63;
  int plocal = p & 3;
  l2[d*4 + plocal] = val;
  float sq = redsum64(val*val);
  if ((t & 63) == 0) wssq[t >> 6] = sq;
  __syncthreads();
  if (t < 64){
    int p0 = j0 >> 6;
    float4 w4 = make_float4(l2[t*4+0], l2[t*4+1], l2[t*4+2], l2[t*4+3]);
    ushort4 h;
    h.x = bfr(w4.x); h.y = bfr(w4.y); h.z = bfr(w4.z); h.w = bfr(w4.w);
    *(ushort4*)(B2T + (size_t)pair*6400 + t*100 + p0) = h;
    psumP[((size_t)pair*25 + jc)*64 + t] = w4.x + w4.y + w4.z + w4.w;
  }
  if (t >= 128 && t < 132){
    int i = t - 128;
    float m = 0.f;
    #pragma unroll
    for (int dd2 = 0; dd2 < 64; dd2++) m += l2[dd2*4 + i];
    MM[pair*100 + (j0 >> 6) + i] = m * (1.f/64.f);
  }
  if (t == 192)
    ssqP[pair*25 + jc] = wssq[0] + wssq[1] + wssq[2] + wssq[3];
}

// ---------------- kVc2: reduce chunk partials -> psum + vninv ----------------
__global__ __launch_bounds__(64) void kVc2(const float* __restrict__ psumP,
                                           const float* __restrict__ ssqP,
                                           float* __restrict__ psum,
                                           float* __restrict__ vninv){
  int pair = blockIdx.x, l = threadIdx.x;
  float s = 0.f;
  #pragma unroll
  for (int c = 0; c < 25; c++) s += psumP[((size_t)pair*25 + c)*64 + l];
  psum[pair*64 + l] = s;
  float sq = (l < 25) ? ssqP[pair*25 + l] : 0.f;
  float tot = redsum64(sq);
  if (l == 0) vninv[pair] = 1.f / fmaxf(sqrtf(tot), 1e-12f);
}

// ---------------- kS v9: 2 queries/lane, bf16 LDS operands, chunk-major A ----------------
// grid 512: qg = b&7 (128 q), fg = b>>3 (K-chunk 100). 4 waves x 18 pairs.
__global__ __launch_bounds__(256) void kS(const float* __restrict__ feat,
                                          const float* __restrict__ invq,
                                          const unsigned short* __restrict__ B2T,
                                          float* __restrict__ sim32){
  __shared__ unsigned short Abf[13*128*8];   // [chunk c][q][8 bf16] : conflict-free reads
  __shared__ unsigned short Bbf[72*104];     // [pr][k] rows, uniform-broadcast reads
  int b = blockIdx.x;
  int qg = b & 7, fg = b >> 3;
  int q0 = qg * 128;
  int fbase = fg * 100;
  int t = threadIdx.x;
  int l = t & 63;
  int wu = __builtin_amdgcn_readfirstlane(t >> 6);
  int pr0 = wu * 18;

  // stage A: 128 q x 25 float4 -> bf16, chunk-major [c][q][8]
  for (int i = t; i < 3200; i += 256){
    int q = i / 25, c4 = i - q*25;
    float4 f4 = *(const float4*)(feat + (size_t)(NS + q0 + q)*6400 + fbase + c4*4);
    float4 v4 = *(const float4*)(invq + (q0 + q)*100 + c4*4);
    ushort4 h;
    h.x = bfr(f4.x*v4.x); h.y = bfr(f4.y*v4.y);
    h.z = bfr(f4.z*v4.z); h.w = bfr(f4.w*v4.w);
    *(ushort4*)(Abf + (c4>>1)*1024 + q*8 + (c4&1)*4) = h;
  }
  // stage B: 72 rows x 25 ushort4 (rows >= 70 zero)
  for (int i = t; i < 1800; i += 256){
    int pr = i / 25, c4 = i - pr*25;
    ushort4 v = make_ushort4(0, 0, 0, 0);
    if (pr < NPAIR) v = *(const ushort4*)(B2T + (size_t)pr*6400 + fbase + c4*4);
    *(ushort4*)(Bbf + pr*104 + c4*4) = v;
  }
  __syncthreads();

  float acc0[18], acc1[18];
  #pragma unroll
  for (int j = 0; j < 18; j++){ acc0[j] = 0.f; acc1[j] = 0.f; }

  #pragma unroll 2
  for (int c = 0; c < 12; c++){
    uint4 aw0 = *(const uint4*)(Abf + c*1024 + l*8);
    uint4 aw1 = *(const uint4*)(Abf + c*1024 + (l + 64)*8);
    float a00 = blo(aw0.x), a01 = bhi(aw0.x), a02 = blo(aw0.y), a03 = bhi(aw0.y);
    float a04 = blo(aw0.z), a05 = bhi(aw0.z), a06 = blo(aw0.w), a07 = bhi(aw0.w);
    float a10 = blo(aw1.x), a11 = bhi(aw1.x), a12 = blo(aw1.y), a13 = bhi(aw1.y);
    float a14 = blo(aw1.z), a15 = bhi(aw1.z), a16 = blo(aw1.w), a17 = bhi(aw1.w);
    int r = c*8;
    #pragma unroll
    for (int j = 0; j < 18; j++){
      uint4 bw = *(const uint4*)(Bbf + (pr0 + j)*104 + r);
      float b0 = blo(bw.x), b1 = bhi(bw.x), b2 = blo(bw.y), b3 = bhi(bw.y);
      float b4 = blo(bw.z), b5 = bhi(bw.z), b6 = blo(bw.w), b7 = bhi(bw.w);
      acc0[j] += a00*b0 + a01*b1 + a02*b2 + a03*b3 + a04*b4 + a05*b5 + a06*b6 + a07*b7;
      acc1[j] += a10*b0 + a11*b1 + a12*b2 + a13*b3 + a14*b4 + a15*b5 + a16*b6 + a17*b7;
    }
  }
  // remainder k = 96..99 (chunk 12, first half)
  {
    uint2 aw0 = *(const uint2*)(Abf + 12*1024 + l*8);
    uint2 aw1 = *(const uint2*)(Abf + 12*1024 + (l + 64)*8);
    float a00 = blo(aw0.x), a01 = bhi(aw0.x), a02 = blo(aw0.y), a03 = bhi(aw0.y);
    float a10 = blo(aw1.x), a11 = bhi(aw1.x), a12 = blo(aw1.y), a13 = bhi(aw1.y);
    #pragma unroll
    for (int j = 0; j < 18; j++){
      uint2 bw = *(const uint2*)(Bbf + (pr0 + j)*104 + 96);
      float b0 = blo(bw.x), b1 = bhi(bw.x), b2 = blo(bw.y), b3 = bhi(bw.y);
      acc0[j] += a00*b0 + a01*b1 + a02*b2 + a03*b3;
      acc1[j] += a10*b0 + a11*b1 + a12*b2 + a13*b3;
    }
  }

  #pragma unroll
  for (int j = 0; j < 18; j++){
    int pr = pr0 + j;
    if (pr < NPAIR){
      sim32[(size_t)fg*SIM_STRIDE + (q0 + l)*NPAIR + pr] = acc0[j];
      sim32[(size_t)fg*SIM_STRIDE + (q0 + l + 64)*NPAIR + pr] = acc1[j];
    }
  }
}

// ---------------- kM: sum 64 f-chunk partials + per-(q,n) softmax over 14 views ----------------
__global__ __launch_bounds__(256) void kM(const float* __restrict__ sim32,
                                          const float* __restrict__ vninv,
                                          const float* __restrict__ temp,
                                          float* __restrict__ pw){
  int t = blockIdx.x*256 + threadIdx.x;
  if (t >= NQ*NWAY) return;
  int q = t / NWAY, n = t - q*NWAY;
  float invT = 1.f / (temp[0] + 1e-6f);
  float s[PRJ];
  #pragma unroll
  for (int v = 0; v < PRJ; v++) s[v] = 0.f;
  for (int c = 0; c < FGROUPS; c++){
    const float* sp = sim32 + (size_t)c*SIM_STRIDE + q*NPAIR + n*PRJ;
    #pragma unroll
    for (int v = 0; v < PRJ; v++) s[v] += sp[v];
  }
  float m = -3.4e38f;
  #pragma unroll
  for (int v = 0; v < PRJ; v++){
    s[v] = s[v] * vninv[n*PRJ + v] * invT;
    m = fmaxf(m, s[v]);
  }
  float sum = 0.f;
  #pragma unroll
  for (int v = 0; v < PRJ; v++){ s[v] = expf(s[v] - m); sum += s[v]; }
  float rs = 1.f / sum;
  #pragma unroll
  for (int v = 0; v < PRJ; v++) pw[q*NPAIR + n*PRJ + v] = s[v] * rs;
}

// ---------------- kP: p-split 4x, sg computed inline, partial outputs ----------------
__global__ __launch_bounds__(256) void kP(const float* __restrict__ vpt,
                                          const float* __restrict__ pw,
                                          const float* __restrict__ MM,
                                          float* __restrict__ pq4){
  __shared__ float sgl[16][PCHUNK];
  int b = blockIdx.x;
  int n  = b / 256;
  int r  = b - n*256;
  int qb = r >> 2;
  int s  = r & 3;
  int p0 = s * PCHUNK;
  int t = threadIdx.x, w = t >> 6, l = t & 63;
  int q0 = qb*16 + w*4;

  float wq[4][PRJ];
  #pragma unroll
  for (int j = 0; j < 4; j++)
    #pragma unroll
    for (int v = 0; v < PRJ; v++)
      wq[j][v] = pw[(q0+j)*NPAIR + n*PRJ + v];

  if (l < PCHUNK){
    #pragma unroll
    for (int j = 0; j < 4; j++){
      float ssg = 0.f;
      #pragma unroll
      for (int v = 0; v < PRJ; v++)
        ssg += wq[j][v] * MM[(n*PRJ + v)*100 + p0 + l];
      sgl[w*4 + j][l] = 1.f / (1.f + expf(-ssg));
    }
  }
  __syncthreads();

  float acc[4] = {0.f, 0.f, 0.f, 0.f};
  const float* vb = vpt + (size_t)n * PRJ * 6400;
  for (int pl = 0; pl < PCHUNK; pl++){
    int p = p0 + pl;
    float vv[PRJ];
    #pragma unroll
    for (int v = 0; v < PRJ; v++) vv[v] = vb[v*6400 + p*64 + l];
    #pragma unroll
    for (int j = 0; j < 4; j++){
      float dot = 0.f;
      #pragma unroll
      for (int v = 0; v < PRJ; v++) dot += wq[j][v] * vv[v];
      acc[j] += sgl[w*4 + j][pl] * dot;
    }
  }
  #pragma unroll
  for (int j = 0; j < 4; j++)
    pq4[(size_t)s*PQ_ELEMS + ((q0+j)*NWAY + n)*64 + l] = acc[j];
}

// ---------------- kF: 5 waves per query, wave = n; pq4-sum and base fused in ----------------
__global__ __launch_bounds__(320) void kF(const float* __restrict__ qv,
                                          const float* __restrict__ pq4,
                                          const float* __restrict__ psum,
                                          const float* __restrict__ Wq,
                                          const float* __restrict__ bq,
                                          const float* __restrict__ Wk,
                                          const float* __restrict__ bk,
                                          const float* __restrict__ gate,
                                          const int*   __restrict__ label,
                                          float* __restrict__ pred,
                                          float* __restrict__ cls,
                                          float* __restrict__ aln){
  __shared__ float qvl[64];
  __shared__ float qp[16];
  __shared__ float scn[NWAY], cosn[NWAY], c2n[NWAY];
  __shared__ float dl5[NWAY][64];
  int q = blockIdx.x, t = threadIdx.x;
  int w = t >> 6, l = t & 63;      // w = n

  float qvv = qv[q*64 + l];
  float qss = redsum64(qvv*qvv);
  float qn8 = fmaxf(sqrtf(qss), 1e-8f);
  if (w == 0) qvl[l] = qvv;
  __syncthreads();
  if (w == 0 && l < 16){
    float s = bq[l];
    #pragma unroll
    for (int d = 0; d < 64; d++) s += qvl[d] * Wq[d*16 + l];
    qp[l] = s;
  }
  __syncthreads();

  float wkq = 0.f;
  #pragma unroll
  for (int e = 0; e < 16; e++) wkq += Wk[l*16 + e] * qp[e];
  float qpb = 0.f;
  #pragma unroll
  for (int e = 0; e < 16; e++) qpb += qp[e] * bk[e];

  size_t idx = (size_t)(q*NWAY + w)*64 + l;
  float x = pq4[idx] + pq4[PQ_ELEMS + idx] + pq4[2*PQ_ELEMS + idx] + pq4[3*PQ_ELEMS + idx];

  float dq = redsum64(qvv * x);
  float ps = redsum64(x * x);
  float cosw = dq / (qn8 * fmaxf(sqrtf(ps), 1e-8f));
  float sd = redsum64(x * wkq);
  float scw = (sd + qpb) * 0.25f;
  if (l == 0){ scn[w] = scw; cosn[w] = cosw; }
  __syncthreads();

  float am = scn[0];
  #pragma unroll
  for (int n = 1; n < NWAY; n++) am = fmaxf(am, scn[n]);
  float asum = 0.f;
  #pragma unroll
  for (int n = 0; n < NWAY; n++) asum += expf(scn[n] - am);
  float attw = expf(scw - am) / asum;

  float g0 = gate[0], g1 = gate[1], g2 = gate[2];
  float gm = fmaxf(fmaxf(g0, g1), g2);
  float e0 = expf(g0 - gm), e1 = expf(g1 - gm), e2 = expf(g2 - gm);
  float gs = 1.f / (e0 + e1 + e2);
  float b0 = (e0 + e1 + e2) * gs;
  float b1 = (e1 + e2) * gs;
  float b2 = e2 * gs;

  float bs = 0.f;
  #pragma unroll
  for (int v = 0; v < PRJ; v++) bs += psum[(w*PRJ + v)*64 + l];
  bs *= (1.f/1400.f);

  float f  = x * attw;
  float dd = fabsf(f - bs);
  dl5[w][l] = dd;
  int rank = 0;
  #pragma unroll 8
  for (int j = 0; j < 64; j++){
    float dj = dl5[w][j];
    rank += (dj > dd) || (dj == dd && j < l);
  }
  float cw = (rank < 16) ? b0 : (rank < 32) ? b1 : (rank < 48) ? b2 : 0.f;
  float gl = f * cw;
  float gss = redsum64(gl * gl);
  float num = redsum64(qvv * gl);
  float c2w = num / (qn8 * fmaxf(sqrtf(gss), 1e-12f));
  if (l == 0) c2n[w] = c2w;
  __syncthreads();

  float mx = c2n[0];
  #pragma unroll
  for (int n = 1; n < NWAY; n++) mx = fmaxf(mx, c2n[n]);
  float psum2 = 0.f;
  #pragma unroll
  for (int n = 0; n < NWAY; n++) psum2 += expf(c2n[n] - mx);
  if (l == 0) pred[q*NWAY + w] = expf(c2w - mx) / psum2;

  if (t == 0){
    int lab = label[q];
    float lm = LAMDA * mx;
    float lsum = 0.f;
    #pragma unroll
    for (int n = 0; n < NWAY; n++) lsum += expf(LAMDA * c2n[n] - lm);
    float c2l = c2n[lab], cosl = cosn[lab];
    float clsv = (lm + logf(lsum)) - LAMDA * c2l;
    float sum5 = 0.f, minn = 3.4e38f;
    #pragma unroll
    for (int n = 0; n < NWAY; n++){
      sum5 += cosn[n];
      if (n != lab) minn = fminf(minn, cosn[n]);
    }
    float hn = (sum5 - cosl - minn) * (1.f/3.f);
    float al = fmaxf(hn - cosl + MARGIN, 0.f);
    cls[q] = clsv; aln[q] = al;
  }
}

// ---------------- kL: loss reduction ----------------
__global__ __launch_bounds__(256) void kL(const float* __restrict__ cls,
                                          const float* __restrict__ aln,
                                          float* __restrict__ out){
  __shared__ float r1[256], r2[256];
  int t = threadIdx.x;
  float s1 = 0.f, s2 = 0.f;
  for (int i = t; i < NQ; i += 256){ s1 += cls[i]; s2 += aln[i]; }
  r1[t] = s1; r2[t] = s2;
  __syncthreads();
  for (int o = 128; o > 0; o >>= 1){
    if (t < o){ r1[t] += r1[t + o]; r2[t] += r2[t + o]; }
    __syncthreads();
  }
  if (t == 0)
    out[NQ*NWAY] = r1[0]*(1.f/NQ) + 0.3f*(r2[0]*(1.f/NQ));
}

extern "C" void kernel_launch(void* const* d_in, const int* in_sizes, int n_in,
                              void* d_out, int out_size, void* d_ws, size_t ws_size,
                              hipStream_t stream){
  const float* feat = (const float*)d_in[0];
  const float* temp = (const float*)d_in[1];
  const float* gate = (const float*)d_in[2];
  const float* Wq   = (const float*)d_in[3];
  const float* bq   = (const float*)d_in[4];
  const float* Wk   = (const float*)d_in[5];
  const float* bk   = (const float*)d_in[6];
  const int*   lab  = (const int*)d_in[7];
  float* out = (float*)d_out;
  float* ws  = (float*)d_ws;

  float* vpt   = ws + VPT_OFF;
  float* vptS  = ws + VPTS_OFF;
  unsigned short* B2T = (unsigned short*)(ws + B2T_OFF);
  float* MMp   = ws + MM_OFF;
  float* vninv = ws + VNINV_OFF;
  float* psum  = ws + PSUM_OFF;
  float* qv    = ws + QV_OFF;
  float* invq  = ws + INVQ_OFF;
  float* sim32 = ws + SIM32_OFF;
  float* pw    = ws + PW_OFF;
  float* pq4   = ws + PQ4_OFF;
  float* cls   = ws + CLS_OFF;
  float* aln   = ws + ALN_OFF;
  float* psumP = ws + PSUMP_OFF;
  float* ssqP  = ws + SSQP_OFF;

  hipLaunchKernelGGL(kN, dim3(NS + NQ), dim3(256), 0, stream, feat, vptS, invq, qv);
  hipLaunchKernelGGL(kVb, dim3(NPAIR*25), dim3(256), 0, stream, vptS, vpt, B2T, MMp, psumP, ssqP);
  hipLaunchKernelGGL(kVc2, dim3(NPAIR), dim3(64), 0, stream, psumP, ssqP, psum, vninv);
  hipLaunchKernelGGL(kS, dim3(8*FGROUPS), dim3(256), 0, stream, feat, invq, B2T, sim32);
  hipLaunchKernelGGL(kM, dim3((NQ*NWAY + 255)/256), dim3(256), 0, stream, sim32, vninv, temp, pw);
  hipLaunchKernelGGL(kP, dim3(NWAY*256), dim3(256), 0, stream, vpt, pw, MMp, pq4);
  hipLaunchKernelGGL(kF, dim3(NQ), dim3(320), 0, stream, qv, pq4, psum, Wq, bq, Wk, bk, gate, lab, out, cls, aln);
  hipLaunchKernelGGL(kL, dim3(1), dim3(256), 0, stream, cls, aln, out);
}

// Round 14
// 99.282 us; speedup vs baseline: 1.6935x; 1.2454x over previous
//
#include <hip/hip_runtime.h>
#include <math.h>

#define NWAY 5
#define KSHOT 5
#define PRJ 14
#define DD 64
#define PP 100
#define NQ 1024
#define NS 350
#define NPAIR 70
#define LAMDA 32.0f
#define MARGIN 0.3f
#define PCHUNK 25
#define FGROUPS 50
#define KCH 128

// ---- workspace layout (floats) ----
#define VPT_OFF   0          // [70][100][64]  = 448000  ([p][d])
#define VPTS_OFF  448000     // [350][6400]    = 2240000
#define B2T_OFF   2688000    // bf16 [70][6400]
#define MM_OFF    3136000    // [70][100]
#define VNINV_OFF 3143000    // [70] pad 128
#define PSUM_OFF  3143128    // [70][64]
#define QV_OFF    3147608    // [1024][64]
#define INVQ_OFF  3213144    // [1024][100]
#define SIM32_OFF 3315544    // [50][1024][70] = 3584000
#define PW_OFF    7903064    // [1024][70]
#define PQ4_OFF   7974744    // [4][1024][5][64]
#define CLS_OFF   9285464    // [1024]
#define ALN_OFF   9286488    // [1024]
#define PSUMP_OFF 9287512    // [70][25][64]
#define SSQP_OFF  9399512    // [70][25]
#define FQBF_OFF  9401344    // bf16 [1024][6400] = 3276800 floats worth (16B aligned)

#define PQ_ELEMS (NQ*NWAY*64)
#define SIM_STRIDE (NQ*NPAIR)

typedef __attribute__((ext_vector_type(8))) short short8;
typedef __attribute__((ext_vector_type(4))) float f32x4;

__device__ __forceinline__ float redsum64(float x){
  #pragma unroll
  for (int o = 1; o < 64; o <<= 1) x += __shfl_xor(x, o, 64);
  return x;
}

// f32 -> bf16 (RNE) bit pack
__device__ __forceinline__ unsigned short bfr(float x){
  unsigned int u = __float_as_uint(x);
  unsigned int r = (u + 0x7FFFu + ((u >> 16) & 1u)) >> 16;
  return (unsigned short)r;
}

// ---------------- kN: per-sample normalize; support -> vptS, query -> featQbf(bf16)+invq+qv ----------------
__global__ __launch_bounds__(256) void kN(const float* __restrict__ feat,
                                          float* __restrict__ vptS,
                                          float* __restrict__ invq,
                                          float* __restrict__ qv,
                                          unsigned short* __restrict__ fqb){
  __shared__ float lds[64*101];
  __shared__ float inv[100];
  int s = blockIdx.x, t = threadIdx.x;
  const float* fp = feat + (size_t)s * 6400;
  #pragma unroll
  for (int i = 0; i < 25; i++){
    int j = t + 256*i;
    int d = j / 100, p = j - d*100;
    lds[d*101 + p] = fp[j];
  }
  __syncthreads();
  if (t < 100){
    float ss = 0.f;
    #pragma unroll
    for (int d = 0; d < 64; d++){ float x = lds[d*101 + t]; ss += x*x; }
    inv[t] = 1.f / fmaxf(sqrtf(ss), 1e-12f);
  }
  __syncthreads();
  if (s < NS){
    #pragma unroll
    for (int i = 0; i < 25; i++){
      int j = t + 256*i;
      int p = j >> 6, d = j & 63;
      vptS[(size_t)s*6400 + j] = lds[d*101 + p] * inv[p];
    }
  } else {
    int q = s - NS;
    #pragma unroll
    for (int i = 0; i < 25; i++){
      int j = t + 256*i;
      int d = j / 100, p = j - d*100;
      fqb[(size_t)q*6400 + j] = bfr(lds[d*101 + p] * inv[p]);
    }
    if (t < 100) invq[q*100 + t] = inv[t];
    if (t < 64){
      float sum = 0.f;
      for (int p = 0; p < PP; p++) sum += lds[t*101 + p] * inv[p];
      qv[q*64 + t] = sum * 0.01f;
    }
  }
}

// ---------------- kVb: sum 5 shots -> vpt + B2T(bf16) + MM + psumP + ssqP ----------------
__global__ __launch_bounds__(256) void kVb(const float* __restrict__ vptS,
                                           float* __restrict__ vpt,
                                           unsigned short* __restrict__ B2T,
                                           float* __restrict__ MM,
                                           float* __restrict__ psumP,
                                           float* __restrict__ ssqP){
  __shared__ float l2[256];
  __shared__ float wssq[4];
  int b = blockIdx.x;
  int pair = b / 25, jc = b - pair*25;
  int n = pair / PRJ, v = pair - n*PRJ;
  int j0 = jc * 256;
  int t = threadIdx.x;
  int j = j0 + t;
  float s = 0.f;
  #pragma unroll
  for (int k = 0; k < KSHOT; k++){
    int sk = (n*KSHOT + k)*PRJ + v;
    s += vptS[(size_t)sk*6400 + j];
  }
  float val = s * 0.2f;
  vpt[(size_t)pair*6400 + j] = val;
  int p = j >> 6, d = j & 63;
  int plocal = p & 3;
  l2[d*4 + plocal] = val;
  float sq = redsum64(val*val);
  if ((t & 63) == 0) wssq[t >> 6] = sq;
  __syncthreads();
  if (t < 64){
    int p0 = j0 >> 6;
    float4 w4 = make_float4(l2[t*4+0], l2[t*4+1], l2[t*4+2], l2[t*4+3]);
    ushort4 h;
    h.x = bfr(w4.x); h.y = bfr(w4.y); h.z = bfr(w4.z); h.w = bfr(w4.w);
    *(ushort4*)(B2T + (size_t)pair*6400 + t*100 + p0) = h;
    psumP[((size_t)pair*25 + jc)*64 + t] = w4.x + w4.y + w4.z + w4.w;
  }
  if (t >= 128 && t < 132){
    int i = t - 128;
    float m = 0.f;
    #pragma unroll
    for (int dd2 = 0; dd2 < 64; dd2++) m += l2[dd2*4 + i];
    MM[pair*100 + (j0 >> 6) + i] = m * (1.f/64.f);
  }
  if (t == 192)
    ssqP[pair*25 + jc] = wssq[0] + wssq[1] + wssq[2] + wssq[3];
}

// ---------------- kVc2: reduce chunk partials -> psum + vninv ----------------
__global__ __launch_bounds__(64) void kVc2(const float* __restrict__ psumP,
                                           const float* __restrict__ ssqP,
                                           float* __restrict__ psum,
                                           float* __restrict__ vninv){
  int pair = blockIdx.x, l = threadIdx.x;
  float s = 0.f;
  #pragma unroll
  for (int c = 0; c < 25; c++) s += psumP[((size_t)pair*25 + c)*64 + l];
  psum[pair*64 + l] = s;
  float sq = (l < 25) ? ssqP[pair*25 + l] : 0.f;
  float tot = redsum64(sq);
  if (l == 0) vninv[pair] = 1.f / fmaxf(sqrtf(tot), 1e-12f);
}

// ---------------- kS v10: pure MFMA, no LDS, A read once, B L2-resident ----------------
// grid 800: fg = b%50 (K-chunk 128 = 4 ksteps), mg = b/50 (4 M-tiles of 16 q).
// wave w owns M-tile mg*4+w; per kstep: 1 A-frag + 5 B-frags + 5 mfma.
__global__ __launch_bounds__(256) void kS(const unsigned short* __restrict__ fqb,
                                          const unsigned short* __restrict__ B2T,
                                          float* __restrict__ sim32){
  int b = blockIdx.x;
  int fg = b % FGROUPS, mg = b / FGROUPS;
  int t = threadIdx.x;
  int l = t & 63;
  int wu = __builtin_amdgcn_readfirstlane(t >> 6);
  int q0 = mg*64 + wu*16;
  int fbase = fg * KCH;

  int lr = l & 15;        // A row / B col / D col
  int kb = l >> 4;        // k-block (8 bf16 each)

  f32x4 acc0 = {0.f,0.f,0.f,0.f};
  f32x4 acc1 = {0.f,0.f,0.f,0.f};
  f32x4 acc2 = {0.f,0.f,0.f,0.f};
  f32x4 acc3 = {0.f,0.f,0.f,0.f};
  f32x4 acc4 = {0.f,0.f,0.f,0.f};

  const unsigned short* Ab = fqb + (size_t)(q0 + lr)*6400 + fbase + kb*8;
  const unsigned short* Bb = B2T + (size_t)lr*6400 + fbase + kb*8;   // + pr0*6400
  bool ok4 = (64 + lr) < NPAIR;

  #pragma unroll
  for (int s = 0; s < 4; s++){
    short8 a = *(const short8*)(Ab + s*32);
    short8 b0 = *(const short8*)(Bb + s*32);
    short8 b1 = *(const short8*)(Bb + 16*6400 + s*32);
    short8 b2 = *(const short8*)(Bb + 32*6400 + s*32);
    short8 b3 = *(const short8*)(Bb + 48*6400 + s*32);
    short8 b4 = ok4 ? *(const short8*)(Bb + (size_t)64*6400 + s*32) : (short8)(short)0;
    acc0 = __builtin_amdgcn_mfma_f32_16x16x32_bf16(a, b0, acc0, 0, 0, 0);
    acc1 = __builtin_amdgcn_mfma_f32_16x16x32_bf16(a, b1, acc1, 0, 0, 0);
    acc2 = __builtin_amdgcn_mfma_f32_16x16x32_bf16(a, b2, acc2, 0, 0, 0);
    acc3 = __builtin_amdgcn_mfma_f32_16x16x32_bf16(a, b3, acc3, 0, 0, 0);
    acc4 = __builtin_amdgcn_mfma_f32_16x16x32_bf16(a, b4, acc4, 0, 0, 0);
  }

  // D layout: col = lr, row = kb*4 + reg
  float* sp = sim32 + (size_t)fg*SIM_STRIDE + (size_t)(q0 + kb*4)*NPAIR;
  #pragma unroll
  for (int i = 0; i < 4; i++){
    sp[(size_t)i*NPAIR + lr]      = acc0[i];
    sp[(size_t)i*NPAIR + 16 + lr] = acc1[i];
    sp[(size_t)i*NPAIR + 32 + lr] = acc2[i];
    sp[(size_t)i*NPAIR + 48 + lr] = acc3[i];
    if (ok4) sp[(size_t)i*NPAIR + 64 + lr] = acc4[i];
  }
}

// ---------------- kM: sum 50 f-chunk partials + per-(q,n) softmax over 14 views ----------------
__global__ __launch_bounds__(256) void kM(const float* __restrict__ sim32,
                                          const float* __restrict__ vninv,
                                          const float* __restrict__ temp,
                                          float* __restrict__ pw){
  int t = blockIdx.x*256 + threadIdx.x;
  if (t >= NQ*NWAY) return;
  int q = t / NWAY, n = t - q*NWAY;
  float invT = 1.f / (temp[0] + 1e-6f);
  float s[PRJ];
  #pragma unroll
  for (int v = 0; v < PRJ; v++) s[v] = 0.f;
  for (int c = 0; c < FGROUPS; c++){
    const float* sp = sim32 + (size_t)c*SIM_STRIDE + q*NPAIR + n*PRJ;
    #pragma unroll
    for (int v = 0; v < PRJ; v++) s[v] += sp[v];
  }
  float m = -3.4e38f;
  #pragma unroll
  for (int v = 0; v < PRJ; v++){
    s[v] = s[v] * vninv[n*PRJ + v] * invT;
    m = fmaxf(m, s[v]);
  }
  float sum = 0.f;
  #pragma unroll
  for (int v = 0; v < PRJ; v++){ s[v] = expf(s[v] - m); sum += s[v]; }
  float rs = 1.f / sum;
  #pragma unroll
  for (int v = 0; v < PRJ; v++) pw[q*NPAIR + n*PRJ + v] = s[v] * rs;
}

// ---------------- kP: p-split 4x, sg computed inline, partial outputs ----------------
__global__ __launch_bounds__(256) void kP(const float* __restrict__ vpt,
                                          const float* __restrict__ pw,
                                          const float* __restrict__ MM,
                                          float* __restrict__ pq4){
  __shared__ float sgl[16][PCHUNK];
  int b = blockIdx.x;
  int n  = b / 256;
  int r  = b - n*256;
  int qb = r >> 2;
  int s  = r & 3;
  int p0 = s * PCHUNK;
  int t = threadIdx.x, w = t >> 6, l = t & 63;
  int q0 = qb*16 + w*4;

  float wq[4][PRJ];
  #pragma unroll
  for (int j = 0; j < 4; j++)
    #pragma unroll
    for (int v = 0; v < PRJ; v++)
      wq[j][v] = pw[(q0+j)*NPAIR + n*PRJ + v];

  if (l < PCHUNK){
    #pragma unroll
    for (int j = 0; j < 4; j++){
      float ssg = 0.f;
      #pragma unroll
      for (int v = 0; v < PRJ; v++)
        ssg += wq[j][v] * MM[(n*PRJ + v)*100 + p0 + l];
      sgl[w*4 + j][l] = 1.f / (1.f + expf(-ssg));
    }
  }
  __syncthreads();

  float acc[4] = {0.f, 0.f, 0.f, 0.f};
  const float* vb = vpt + (size_t)n * PRJ * 6400;
  for (int pl = 0; pl < PCHUNK; pl++){
    int p = p0 + pl;
    float vv[PRJ];
    #pragma unroll
    for (int v = 0; v < PRJ; v++) vv[v] = vb[v*6400 + p*64 + l];
    #pragma unroll
    for (int j = 0; j < 4; j++){
      float dot = 0.f;
      #pragma unroll
      for (int v = 0; v < PRJ; v++) dot += wq[j][v] * vv[v];
      acc[j] += sgl[w*4 + j][pl] * dot;
    }
  }
  #pragma unroll
  for (int j = 0; j < 4; j++)
    pq4[(size_t)s*PQ_ELEMS + ((q0+j)*NWAY + n)*64 + l] = acc[j];
}

// ---------------- kF: 5 waves per query, wave = n; pq4-sum and base fused in ----------------
__global__ __launch_bounds__(320) void kF(const float* __restrict__ qv,
                                          const float* __restrict__ pq4,
                                          const float* __restrict__ psum,
                                          const float* __restrict__ Wq,
                                          const float* __restrict__ bq,
                                          const float* __restrict__ Wk,
                                          const float* __restrict__ bk,
                                          const float* __restrict__ gate,
                                          const int*   __restrict__ label,
                                          float* __restrict__ pred,
                                          float* __restrict__ cls,
                                          float* __restrict__ aln){
  __shared__ float qvl[64];
  __shared__ float qp[16];
  __shared__ float scn[NWAY], cosn[NWAY], c2n[NWAY];
  __shared__ float dl5[NWAY][64];
  int q = blockIdx.x, t = threadIdx.x;
  int w = t >> 6, l = t & 63;      // w = n

  float qvv = qv[q*64 + l];
  float qss = redsum64(qvv*qvv);
  float qn8 = fmaxf(sqrtf(qss), 1e-8f);
  if (w == 0) qvl[l] = qvv;
  __syncthreads();
  if (w == 0 && l < 16){
    float s = bq[l];
    #pragma unroll
    for (int d = 0; d < 64; d++) s += qvl[d] * Wq[d*16 + l];
    qp[l] = s;
  }
  __syncthreads();

  float wkq = 0.f;
  #pragma unroll
  for (int e = 0; e < 16; e++) wkq += Wk[l*16 + e] * qp[e];
  float qpb = 0.f;
  #pragma unroll
  for (int e = 0; e < 16; e++) qpb += qp[e] * bk[e];

  size_t idx = (size_t)(q*NWAY + w)*64 + l;
  float x = pq4[idx] + pq4[PQ_ELEMS + idx] + pq4[2*PQ_ELEMS + idx] + pq4[3*PQ_ELEMS + idx];

  float dq = redsum64(qvv * x);
  float ps = redsum64(x * x);
  float cosw = dq / (qn8 * fmaxf(sqrtf(ps), 1e-8f));
  float sd = redsum64(x * wkq);
  float scw = (sd + qpb) * 0.25f;
  if (l == 0){ scn[w] = scw; cosn[w] = cosw; }
  __syncthreads();

  float am = scn[0];
  #pragma unroll
  for (int n = 1; n < NWAY; n++) am = fmaxf(am, scn[n]);
  float asum = 0.f;
  #pragma unroll
  for (int n = 0; n < NWAY; n++) asum += expf(scn[n] - am);
  float attw = expf(scw - am) / asum;

  float g0 = gate[0], g1 = gate[1], g2 = gate[2];
  float gm = fmaxf(fmaxf(g0, g1), g2);
  float e0 = expf(g0 - gm), e1 = expf(g1 - gm), e2 = expf(g2 - gm);
  float gs = 1.f / (e0 + e1 + e2);
  float b0 = (e0 + e1 + e2) * gs;
  float b1 = (e1 + e2) * gs;
  float b2 = e2 * gs;

  float bs = 0.f;
  #pragma unroll
  for (int v = 0; v < PRJ; v++) bs += psum[(w*PRJ + v)*64 + l];
  bs *= (1.f/1400.f);

  float f  = x * attw;
  float dd = fabsf(f - bs);
  dl5[w][l] = dd;
  int rank = 0;
  #pragma unroll 8
  for (int j = 0; j < 64; j++){
    float dj = dl5[w][j];
    rank += (dj > dd) || (dj == dd && j < l);
  }
  float cw = (rank < 16) ? b0 : (rank < 32) ? b1 : (rank < 48) ? b2 : 0.f;
  float gl = f * cw;
  float gss = redsum64(gl * gl);
  float num = redsum64(qvv * gl);
  float c2w = num / (qn8 * fmaxf(sqrtf(gss), 1e-12f));
  if (l == 0) c2n[w] = c2w;
  __syncthreads();

  float mx = c2n[0];
  #pragma unroll
  for (int n = 1; n < NWAY; n++) mx = fmaxf(mx, c2n[n]);
  float psum2 = 0.f;
  #pragma unroll
  for (int n = 0; n < NWAY; n++) psum2 += expf(c2n[n] - mx);
  if (l == 0) pred[q*NWAY + w] = expf(c2w - mx) / psum2;

  if (t == 0){
    int lab = label[q];
    float lm = LAMDA * mx;
    float lsum = 0.f;
    #pragma unroll
    for (int n = 0; n < NWAY; n++) lsum += expf(LAMDA * c2n[n] - lm);
    float c2l = c2n[lab], cosl = cosn[lab];
    float clsv = (lm + logf(lsum)) - LAMDA * c2l;
    float sum5 = 0.f, minn = 3.4e38f;
    #pragma unroll
    for (int n = 0; n < NWAY; n++){
      sum5 += cosn[n];
      if (n != lab) minn = fminf(minn, cosn[n]);
    }
    float hn = (sum5 - cosl - minn) * (1.f/3.f);
    float al = fmaxf(hn - cosl + MARGIN, 0.f);
    cls[q] = clsv; aln[q] = al;
  }
}

// ---------------- kL: loss reduction ----------------
__global__ __launch_bounds__(256) void kL(const float* __restrict__ cls,
                                          const float* __restrict__ aln,
                                          float* __restrict__ out){
  __shared__ float r1[256], r2[256];
  int t = threadIdx.x;
  float s1 = 0.f, s2 = 0.f;
  for (int i = t; i < NQ; i += 256){ s1 += cls[i]; s2 += aln[i]; }
  r1[t] = s1; r2[t] = s2;
  __syncthreads();
  for (int o = 128; o > 0; o >>= 1){
    if (t < o){ r1[t] += r1[t + o]; r2[t] += r2[t + o]; }
    __syncthreads();
  }
  if (t == 0)
    out[NQ*NWAY] = r1[0]*(1.f/NQ) + 0.3f*(r2[0]*(1.f/NQ));
}

extern "C" void kernel_launch(void* const* d_in, const int* in_sizes, int n_in,
                              void* d_out, int out_size, void* d_ws, size_t ws_size,
                              hipStream_t stream){
  const float* feat = (const float*)d_in[0];
  const float* temp = (const float*)d_in[1];
  const float* gate = (const float*)d_in[2];
  const float* Wq   = (const float*)d_in[3];
  const float* bq   = (const float*)d_in[4];
  const float* Wk   = (const float*)d_in[5];
  const float* bk   = (const float*)d_in[6];
  const int*   lab  = (const int*)d_in[7];
  float* out = (float*)d_out;
  float* ws  = (float*)d_ws;

  float* vpt   = ws + VPT_OFF;
  float* vptS  = ws + VPTS_OFF;
  unsigned short* B2T = (unsigned short*)(ws + B2T_OFF);
  float* MMp   = ws + MM_OFF;
  float* vninv = ws + VNINV_OFF;
  float* psum  = ws + PSUM_OFF;
  float* qv    = ws + QV_OFF;
  float* invq  = ws + INVQ_OFF;
  float* sim32 = ws + SIM32_OFF;
  float* pw    = ws + PW_OFF;
  float* pq4   = ws + PQ4_OFF;
  float* cls   = ws + CLS_OFF;
  float* aln   = ws + ALN_OFF;
  float* psumP = ws + PSUMP_OFF;
  float* ssqP  = ws + SSQP_OFF;
  unsigned short* fqb = (unsigned short*)(ws + FQBF_OFF);

  hipLaunchKernelGGL(kN, dim3(NS + NQ), dim3(256), 0, stream, feat, vptS, invq, qv, fqb);
  hipLaunchKernelGGL(kVb, dim3(NPAIR*25), dim3(256), 0, stream, vptS, vpt, B2T, MMp, psumP, ssqP);
  hipLaunchKernelGGL(kVc2, dim3(NPAIR), dim3(64), 0, stream, psumP, ssqP, psum, vninv);
  hipLaunchKernelGGL(kS, dim3(16*FGROUPS), dim3(256), 0, stream, fqb, B2T, sim32);
  hipLaunchKernelGGL(kM, dim3((NQ*NWAY + 255)/256), dim3(256), 0, stream, sim32, vninv, temp, pw);
  hipLaunchKernelGGL(kP, dim3(NWAY*256), dim3(256), 0, stream, vpt, pw, MMp, pq4);
  hipLaunchKernelGGL(kF, dim3(NQ), dim3(320), 0, stream, qv, pq4, psum, Wq, bq, Wk, bk, gate, lab, out, cls, aln);
  hipLaunchKernelGGL(kL, dim3(1), dim3(256), 0, stream, cls, aln, out);
}